// Round 9
// baseline (279.235 us; speedup 1.0000x reference)
//
#include <hip/hip_runtime.h>
#include <hip/hip_bf16.h>
#include <cstdint>
#include <cstddef>

#define D_IN  128
#define D_H   256
#define D_OUT 64

typedef __attribute__((ext_vector_type(4))) float f32x4;
typedef __attribute__((ext_vector_type(8))) short s16x8;

__device__ __forceinline__ unsigned short f2bf(float f) {
  unsigned u = __float_as_uint(f);
  return (unsigned short)((u + 0x7fffu + ((u >> 16) & 1u)) >> 16);
}
__device__ __forceinline__ float bf2f(unsigned short b) {
  return __uint_as_float(((unsigned)b) << 16);
}

// ---------------- fused prep: zero counters, pad zb, extract edges ----------------
__global__ void prep_k(const int* __restrict__ raw, int* __restrict__ cnt,
                       int* __restrict__ cursor, int* __restrict__ gmax,
                       unsigned short* __restrict__ zb, int* __restrict__ src,
                       int* __restrict__ dst, int n, int npadElems, int E) {
  __shared__ int flag;
  if (threadIdx.x == 0) {
    int zeros = 0;
    for (int i = 0; i < 64; ++i) zeros += (raw[2 * i + 1] == 0) ? 1 : 0;
    flag = (zeros >= 60) ? 1 : 0;  // int64 storage: odd words are zero high halves
  }
  __syncthreads();
  int is64 = flag;
  int T = n + 1 + npadElems + E;
  int idx = blockIdx.x * blockDim.x + threadIdx.x;
  int stride = gridDim.x * blockDim.x;
  for (; idx < T; idx += stride) {
    if (idx < n) { cnt[idx] = 0; cursor[idx] = 0; }
    else if (idx == n) gmax[0] = 0;
    else if (idx < n + 1 + npadElems) zb[(size_t)n * D_OUT + (idx - (n + 1))] = 0;
    else {
      int e = idx - (n + 1 + npadElems);
      if (is64) { src[e] = raw[2 * e]; dst[e] = raw[2 * (E + e)]; }
      else      { src[e] = raw[e];     dst[e] = raw[E + e]; }
    }
  }
}

// ---------------- degree count ----------------
__global__ void count_k(const int* __restrict__ dst, int* cnt, int E) {
  int idx = blockIdx.x * blockDim.x + threadIdx.x;
  int stride = gridDim.x * blockDim.x;
  for (; idx < E; idx += stride) atomicAdd(&cnt[dst[idx]], 1);
}

// ---------------- exclusive scan (shfl-based, 2 barriers) + dinv fused ----------------
__global__ void scan_k(const int* __restrict__ cnt, int* __restrict__ offs,
                       float* __restrict__ dinv, int n) {
  int t = threadIdx.x;
  int lane = t & 63, wv = t >> 6;
  const int CH = 10;
  int base = t * CH;
  int local[CH];
  int s = 0;
  for (int i = 0; i < CH; ++i) {
    int v = (base + i < n) ? cnt[base + i] : 0;
    if (base + i < n) dinv[base + i] = rsqrtf((float)v + 1.0f);
    local[i] = s;
    s += v;
  }
  int sc = s;                              // wave-inclusive scan of per-thread sums
  for (int o = 1; o < 64; o <<= 1) {
    int u = __shfl_up(sc, o, 64);
    if (lane >= o) sc += u;
  }
  __shared__ int wtot[16];
  if (lane == 63) wtot[wv] = sc;
  __syncthreads();
  if (t == 0) {
    int a = 0;
    for (int i = 0; i < 16; ++i) { int v = wtot[i]; wtot[i] = a; a += v; }
  }
  __syncthreads();
  int prefix = wtot[wv] + (sc - s);        // exclusive prefix for this thread
  for (int i = 0; i < CH; ++i)
    if (base + i < n) offs[base + i] = prefix + local[i];
  if (t == 1023) offs[n] = prefix + s;
}

// ---------------- fill CSR ----------------
__global__ void fill_k(const int* __restrict__ src, const int* __restrict__ dst,
                       const int* __restrict__ offs, int* __restrict__ cursor,
                       const float* __restrict__ dinv, int* __restrict__ csr_src,
                       float* __restrict__ csr_norm, int E) {
  int idx = blockIdx.x * blockDim.x + threadIdx.x;
  int stride = gridDim.x * blockDim.x;
  for (; idx < E; idx += stride) {
    int d = dst[idx], s = src[idx];
    int pos = atomicAdd(&cursor[d], 1);
    int slot = offs[d] + pos;
    csr_src[slot] = s;
    csr_norm[slot] = dinv[s] * dinv[d];
  }
}

// ---------------- layer-1 GEMM (fp32 VALU, bf16 OUTPUT after full fp32 accumulate) ----------------
// R8 lesson: bf16 INPUTS to the GEMMs (x, W1, h1, W2) stacked ~9x error (absmax
// 0.035 > 0.02). Post-accumulation bf16 output (here) passed at 9x margin. Keep
// the encoder GEMM math in fp32.
__global__ void gemm1_k(const float* __restrict__ A, const float* __restrict__ B,
                        unsigned short* __restrict__ C, int M, int N, int K) {
  __shared__ float As[16][64];
  __shared__ float Bs[16][64];
  int t = threadIdx.x;
  int bm = blockIdx.x * 64, bn = blockIdx.y * 64;
  int tx = t & 15, ty = t >> 4;
  int lr = t >> 2;
  int lk = (t & 3) * 4;
  int br = t >> 4;
  int bc = (t & 15) * 4;
  float acc[4][4] = {};
  for (int k0 = 0; k0 < K; k0 += 16) {
    float4 av = make_float4(0.f, 0.f, 0.f, 0.f);
    if (bm + lr < M) av = *(const float4*)&A[(size_t)(bm + lr) * K + k0 + lk];
    As[lk + 0][lr] = av.x;
    As[lk + 1][lr] = av.y;
    As[lk + 2][lr] = av.z;
    As[lk + 3][lr] = av.w;
    float4 bv = *(const float4*)&B[(size_t)(k0 + br) * N + bn + bc];
    *(float4*)&Bs[br][bc] = bv;
    __syncthreads();
#pragma unroll
    for (int k = 0; k < 16; ++k) {
      float4 a = *(const float4*)&As[k][ty * 4];
      float4 b = *(const float4*)&Bs[k][tx * 4];
      acc[0][0] += a.x * b.x; acc[0][1] += a.x * b.y; acc[0][2] += a.x * b.z; acc[0][3] += a.x * b.w;
      acc[1][0] += a.y * b.x; acc[1][1] += a.y * b.y; acc[1][2] += a.y * b.z; acc[1][3] += a.y * b.w;
      acc[2][0] += a.z * b.x; acc[2][1] += a.z * b.y; acc[2][2] += a.z * b.z; acc[2][3] += a.z * b.w;
      acc[3][0] += a.w * b.x; acc[3][1] += a.w * b.y; acc[3][2] += a.w * b.z; acc[3][3] += a.w * b.w;
    }
    __syncthreads();
  }
  for (int r = 0; r < 4; ++r) {
    int row = bm + ty * 4 + r;
    if (row < M) {
      ushort4 o;
      o.x = f2bf(acc[r][0]); o.y = f2bf(acc[r][1]);
      o.z = f2bf(acc[r][2]); o.w = f2bf(acc[r][3]);
      *(ushort4*)&C[(size_t)row * N + bn + tx * 4] = o;
    }
  }
}

// ---------------- layer-2 GEMM: BM=32,BN=64,BK=16 -> 313 blocks (fills 256 CUs) ----------------
__global__ void gemm2_k(const float* __restrict__ A, const float* __restrict__ B,
                        float* __restrict__ C, int M, int N, int K) {
  __shared__ float As[16][32];
  __shared__ float Bs[16][64];
  int t = threadIdx.x;
  int bm = blockIdx.x * 32;
  int tx = t & 15, ty = t >> 4;       // ty 0..15 -> 2 rows each; tx -> 4 cols
  int lr = t >> 3;                    // A-load row 0..31
  int lkk = (t & 7) * 2;              // A-load k offset (float2)
  int br = t >> 4;                    // B-load k row 0..15
  int bc = (t & 15) * 4;              // B-load col
  float acc[2][4] = {};
  for (int k0 = 0; k0 < K; k0 += 16) {
    float2 av = make_float2(0.f, 0.f);
    if (bm + lr < M) av = *(const float2*)&A[(size_t)(bm + lr) * K + k0 + lkk];
    As[lkk + 0][lr] = av.x;
    As[lkk + 1][lr] = av.y;
    float4 bv = *(const float4*)&B[(size_t)(k0 + br) * N + bc];
    *(float4*)&Bs[br][bc] = bv;
    __syncthreads();
#pragma unroll
    for (int k = 0; k < 16; ++k) {
      float a0 = As[k][ty * 2], a1 = As[k][ty * 2 + 1];
      float4 b = *(const float4*)&Bs[k][tx * 4];
      acc[0][0] += a0 * b.x; acc[0][1] += a0 * b.y; acc[0][2] += a0 * b.z; acc[0][3] += a0 * b.w;
      acc[1][0] += a1 * b.x; acc[1][1] += a1 * b.y; acc[1][2] += a1 * b.z; acc[1][3] += a1 * b.w;
    }
    __syncthreads();
  }
  for (int r = 0; r < 2; ++r) {
    int row = bm + ty * 2 + r;
    if (row < M)
      *(float4*)&C[(size_t)row * N + tx * 4] =
          make_float4(acc[r][0], acc[r][1], acc[r][2], acc[r][3]);
  }
}

// ---------------- GCN aggregation layer 1 (D_H=256), wave per node, bf16 h in, fp32 out ----------------
__global__ void agg1_k(const unsigned short* __restrict__ hb, const int* __restrict__ offs,
                       const int* __restrict__ csr_src, const float* __restrict__ csr_norm,
                       const float* __restrict__ dinv, const float* __restrict__ b1,
                       float* __restrict__ h1, int n) {
  int wid = blockIdx.x * 4 + (threadIdx.x >> 6);
  int lane = threadIdx.x & 63;
  if (wid >= n) return;
  const ushort4* hb4 = (const ushort4*)hb;
  float di = dinv[wid];
  float selfw = di * di;
  float4 acc = *(const float4*)&b1[lane * 4];
  ushort4 sv = hb4[(size_t)wid * 64 + lane];
  acc.x += bf2f(sv.x) * selfw; acc.y += bf2f(sv.y) * selfw;
  acc.z += bf2f(sv.z) * selfw; acc.w += bf2f(sv.w) * selfw;
  int e0 = offs[wid], e1 = offs[wid + 1];
  for (int e = e0; e < e1; ++e) {
    int s = csr_src[e];
    float w = csr_norm[e];
    ushort4 v = hb4[(size_t)s * 64 + lane];
    acc.x += bf2f(v.x) * w; acc.y += bf2f(v.y) * w;
    acc.z += bf2f(v.z) * w; acc.w += bf2f(v.w) * w;
  }
  acc.x = fmaxf(acc.x, 0.f); acc.y = fmaxf(acc.y, 0.f);
  acc.z = fmaxf(acc.z, 0.f); acc.w = fmaxf(acc.w, 0.f);
  *(float4*)&h1[(size_t)wid * D_H + lane * 4] = acc;
}

// ---------------- GCN aggregation layer 2 (D_OUT=64): z->bf16, sq from ROUNDED z ----------------
__global__ void agg2_k(const float* __restrict__ h2, const int* __restrict__ offs,
                       const int* __restrict__ csr_src, const float* __restrict__ csr_norm,
                       const float* __restrict__ dinv, const float* __restrict__ b2,
                       unsigned short* __restrict__ zb, float* __restrict__ sq, int n) {
  int wid = blockIdx.x * 4 + (threadIdx.x >> 6);
  int lane = threadIdx.x & 63;
  if (wid >= n) return;
  float di = dinv[wid];
  float selfw = di * di;
  float acc = b2[lane] + h2[(size_t)wid * D_OUT + lane] * selfw;
  int e0 = offs[wid], e1 = offs[wid + 1];
  for (int e = e0; e < e1; ++e) {
    int s = csr_src[e];
    float w = csr_norm[e];
    acc += h2[(size_t)s * D_OUT + lane] * w;
  }
  unsigned short rb = f2bf(acc);
  zb[(size_t)wid * D_OUT + lane] = rb;
  float back = bf2f(rb);
  float ss = back * back;
#pragma unroll
  for (int o = 32; o > 0; o >>= 1) ss += __shfl_xor(ss, o, 64);
  if (lane == 0) sq[wid] = ss;
}

// ---------------- MFMA decode: 128x128 tile, bf16 Z @ Z^T, K=64 ----------------
// mode 0: upper-triangle grid, per-block max(d2) via plain store (single-address
// atomicMax serialized 260us in R5). mode 1: full grid,
// out = 1 - d2*rsqrt(d2)*rsqrt(m2)  (v_rsq_f32, ~1e-7 rel; precise sqrtf is a
// multi-instr IEEE expansion x64/lane).
__global__ __launch_bounds__(256, 1) void decode_mfma_k(
    const unsigned short* __restrict__ zb, const float* __restrict__ sq,
    float* __restrict__ out, float* __restrict__ blockmax,
    const int* __restrict__ gmax, int n, int mode) {
  __shared__ __align__(16) char ZiB[128 * 128];
  __shared__ __align__(16) char ZjB[128 * 128];
  __shared__ float sqi[128];
  __shared__ float sqj[128];
  __shared__ float wmax[4];
  int t = threadIdx.x;

  int bi, bj;
  if (mode == 0) {
    int b = blockIdx.x;                       // b = bj*(bj+1)/2 + bi, bi <= bj
    int tj = (int)((sqrtf(8.f * (float)b + 1.f) - 1.f) * 0.5f);
    while ((tj + 1) * (tj + 2) / 2 <= b) ++tj;
    while (tj * (tj + 1) / 2 > b) --tj;
    bj = tj;
    bi = b - tj * (tj + 1) / 2;
  } else {
    bi = blockIdx.y; bj = blockIdx.x;
  }
  int i0 = bi * 128, j0 = bj * 128;

#pragma unroll
  for (int it = 0; it < 4; ++it) {
    int c = t + it * 256;
    int row = c >> 3, s = c & 7;
    int dstb = row * 128 + ((s * 16) ^ ((row & 7) << 4));
    s16x8 vi = *(const s16x8*)&zb[(size_t)(i0 + row) * D_OUT + s * 8];
    *(s16x8*)&ZiB[dstb] = vi;
    s16x8 vj = *(const s16x8*)&zb[(size_t)(j0 + row) * D_OUT + s * 8];
    *(s16x8*)&ZjB[dstb] = vj;
  }
  if (t < 128) sqi[t] = (i0 + t < n) ? sq[i0 + t] : 0.f;
  else { int tt = t - 128; sqj[tt] = (j0 + tt < n) ? sq[j0 + tt] : 0.f; }
  __syncthreads();

  int lane = t & 63;
  int wid = t >> 6;
  int wr = (wid >> 1) * 64;
  int wc = (wid & 1) * 64;
  int lrow = lane & 15;
  int lgrp = lane >> 4;
  int swz = (lrow & 7) << 4;

  f32x4 acc[4][4] = {};
#pragma unroll
  for (int ks = 0; ks < 2; ++ks) {
    s16x8 a[4], b[4];
    int kb = (ks * 64) ^ (lgrp * 16) ^ swz;
#pragma unroll
    for (int q = 0; q < 4; ++q) {
      a[q] = *(const s16x8*)&ZiB[(wr + q * 16 + lrow) * 128 + kb];
      b[q] = *(const s16x8*)&ZjB[(wc + q * 16 + lrow) * 128 + kb];
    }
#pragma unroll
    for (int rt = 0; rt < 4; ++rt)
#pragma unroll
      for (int ct = 0; ct < 4; ++ct)
        acc[rt][ct] = __builtin_amdgcn_mfma_f32_16x16x32_bf16(a[rt], b[ct], acc[rt][ct], 0, 0, 0);
  }

  float sqa[4][4], sqb[4];
#pragma unroll
  for (int rt = 0; rt < 4; ++rt)
#pragma unroll
    for (int reg = 0; reg < 4; ++reg)
      sqa[rt][reg] = sqi[wr + rt * 16 + lgrp * 4 + reg];
#pragma unroll
  for (int ct = 0; ct < 4; ++ct) sqb[ct] = sqj[wc + ct * 16 + lrow];

  if (mode == 0) {
    float lmax = 0.f;
#pragma unroll
    for (int rt = 0; rt < 4; ++rt)
#pragma unroll
      for (int ct = 0; ct < 4; ++ct)
#pragma unroll
        for (int reg = 0; reg < 4; ++reg) {
          int i = i0 + wr + rt * 16 + lgrp * 4 + reg;
          int j = j0 + wc + ct * 16 + lrow;
          if (i < n && j < n) {   // exclude ghosts: d2_ghost = |z_valid|^2 > 0 (R3 bug)
            float d2 = sqa[rt][reg] + sqb[ct] - 2.f * acc[rt][ct][reg];
            lmax = fmaxf(lmax, d2);
          }
        }
#pragma unroll
    for (int o = 32; o > 0; o >>= 1) lmax = fmaxf(lmax, __shfl_xor(lmax, o, 64));
    if (lane == 0) wmax[wid] = lmax;
    __syncthreads();
    if (t == 0) {
      float m = fmaxf(fmaxf(wmax[0], wmax[1]), fmaxf(wmax[2], wmax[3]));
      blockmax[blockIdx.x] = m;  // disjoint store, no atomic
    }
  } else {
    float m2 = __int_as_float(*gmax);
    float rsm = (m2 > 0.f) ? rsqrtf(m2) : 0.f;
#pragma unroll
    for (int rt = 0; rt < 4; ++rt)
#pragma unroll
      for (int reg = 0; reg < 4; ++reg) {
        int i = i0 + wr + rt * 16 + lgrp * 4 + reg;
        if (i >= n) continue;
        size_t rowbase = (size_t)i * n;
#pragma unroll
        for (int ct = 0; ct < 4; ++ct) {
          int j = j0 + wc + ct * 16 + lrow;
          if (j >= n) continue;
          float d2 = fmaxf(sqa[rt][reg] + sqb[ct] - 2.f * acc[rt][ct][reg], 1e-30f);
          out[rowbase + j] = 1.f - d2 * rsqrtf(d2) * rsm;  // clamped d2 -> ~1 (diagonal)
        }
      }
  }
}

// ---------------- reduce block maxes -> gmax (single block) ----------------
__global__ void reduce_k(const float* __restrict__ bm, int* __restrict__ gmax, int nb) {
  __shared__ float s[1024];
  int t = threadIdx.x;
  float m = 0.f;
  for (int i = t; i < nb; i += 1024) m = fmaxf(m, bm[i]);
  s[t] = m;
  __syncthreads();
  for (int o = 512; o > 0; o >>= 1) {
    if (t < o) s[t] = fmaxf(s[t], s[t + o]);
    __syncthreads();
  }
  if (t == 0) gmax[0] = __float_as_int(s[0]);
}

extern "C" void kernel_launch(void* const* d_in, const int* in_sizes, int n_in,
                              void* d_out, int out_size, void* d_ws, size_t ws_size,
                              hipStream_t stream) {
  const float* x  = (const float*)d_in[0];
  const int* eraw = (const int*)d_in[1];
  const float* W1 = (const float*)d_in[2];
  const float* b1 = (const float*)d_in[3];
  const float* W2 = (const float*)d_in[4];
  const float* b2 = (const float*)d_in[5];
  float* out = (float*)d_out;

  const int n = in_sizes[0] / D_IN;   // 10000
  const int E = in_sizes[1] / 2;      // 320000
  const int gt = (n + 127) / 128;     // 79
  const int n_pad = gt * 128;         // 10112
  const int nbU = gt * (gt + 1) / 2;  // 3160 upper-triangle blocks

  // workspace carve (256B aligned)
  char* p = (char*)d_ws;
  auto alloc = [&](size_t bytes) {
    void* r = (void*)p;
    p += (bytes + 255) & ~(size_t)255;
    return r;
  };
  int*   cnt      = (int*)alloc((size_t)n * 4);
  int*   offs     = (int*)alloc((size_t)(n + 1) * 4);
  int*   cursor   = (int*)alloc((size_t)n * 4);
  int*   esrc     = (int*)alloc((size_t)E * 4);
  int*   edst     = (int*)alloc((size_t)E * 4);
  int*   csr_src  = (int*)alloc((size_t)E * 4);
  float* csr_norm = (float*)alloc((size_t)E * 4);
  float* dinv     = (float*)alloc((size_t)n * 4);
  unsigned short* hb = (unsigned short*)alloc((size_t)n * D_H * 2);
  float* h1       = (float*)alloc((size_t)n * D_H * 4);
  float* h2       = (float*)alloc((size_t)n * D_OUT * 4);
  unsigned short* zbuf = (unsigned short*)alloc((size_t)n_pad * D_OUT * 2);
  float* sq       = (float*)alloc((size_t)n * 4);
  float* blockmax = (float*)alloc((size_t)nbU * 4);
  int*   gmax     = (int*)alloc(4);

  const int npadElems = (n_pad - n) * D_OUT;
  const int prepT = n + 1 + npadElems + E;
  prep_k<<<(prepT + 255) / 256, 256, 0, stream>>>(eraw, cnt, cursor, gmax, zbuf,
                                                  esrc, edst, n, npadElems, E);
  count_k<<<512, 256, 0, stream>>>(edst, cnt, E);
  scan_k<<<1, 1024, 0, stream>>>(cnt, offs, dinv, n);
  fill_k<<<512, 256, 0, stream>>>(esrc, edst, offs, cursor, dinv, csr_src, csr_norm, E);

  // layer 1: hb = bf16(x @ W1) (fp32 accumulate) ; h1 = relu(agg(hb)) fp32
  gemm1_k<<<dim3((n + 63) / 64, D_H / 64), 256, 0, stream>>>(x, W1, hb, n, D_H, D_IN);
  agg1_k<<<(n + 3) / 4, 256, 0, stream>>>(hb, offs, csr_src, csr_norm, dinv, b1, h1, n);

  // layer 2: h2 = h1 @ W2 fp32 ; z(bf16), sq = agg(h2)
  gemm2_k<<<(n + 31) / 32, 256, 0, stream>>>(h1, W2, h2, n, D_OUT, D_H);
  agg2_k<<<(n + 3) / 4, 256, 0, stream>>>(h2, offs, csr_src, csr_norm, dinv, b2, zbuf, sq, n);

  // decode: pass 0 = upper-tri per-block max(d2), reduce, pass 1 = full write
  decode_mfma_k<<<nbU, 256, 0, stream>>>(zbuf, sq, out, blockmax, gmax, n, 0);
  reduce_k<<<1, 1024, 0, stream>>>(blockmax, gmax, nbU);
  decode_mfma_k<<<dim3(gt, gt), 256, 0, stream>>>(zbuf, sq, out, blockmax, gmax, n, 1);
}